// Round 10
// baseline (544.676 us; speedup 1.0000x reference)
//
#include <hip/hip_runtime.h>
#include <math.h>
#include <cstddef>

// Problem constants
#define BB   16
#define HH   256
#define WW   256
#define CC   64      // channels (= attention token count)
#define NTOK 16      // pooled tokens per (b,c)
#define NDIM 16      // DIM
#define HALF_B 8

// ws layout:
//   part : [B][16 tok][16 rc][64 c] fp32  = 262144 floats (1 MiB)
//   frag : [B][8 slot][64 lane][8 j] bf16 =  65536 ushorts (128 KiB)
//     per-batch: 8*64*8 = 4096 ushorts = 512 fragments of 16 B.
//     slot = tt*2 + kstep
//     element: W[t = tt*16 + (lane&15)][c = kstep*32 + (lane>>4)*8 + j]
//   SINGLE bf16: attn ~= 1/64 uniform, out in +-0.8; single-RNE-bf16 error
//   max ~1e-3 << 8.7e-3 budget (verified r6-r9, absmax at harness floor).
#define PART_FLOATS (BB * NTOK * 16 * CC)
#define FRAG_USHORT_PER_B (8 * 64 * 8)   // 4096

typedef short s16x8 __attribute__((ext_vector_type(8)));   // 8 bf16 (4 VGPRs)
typedef float f32x4 __attribute__((ext_vector_type(4)));

__device__ __forceinline__ unsigned short f2bf_rne(float f) {
    unsigned int u = __float_as_uint(f);
    return (unsigned short)((u + 0x7fffu + ((u >> 16) & 1u)) >> 16);
}

// ---------------------------------------------------------------------------
// Pool body (shared by standalone kernel and fused kernel). blk encodes
// b*256 + n*16 + rc. Near coalesced-read floor.
// ---------------------------------------------------------------------------
__device__ __forceinline__ void pool_body(const float* __restrict__ x,
                                          float* __restrict__ part, int blk) {
    const int rc  = blk & 15;
    const int n   = (blk >> 4) & 15;
    const int b   = blk >> 8;
    const int ph  = n >> 2, pw = n & 3;
    const int t   = threadIdx.x;
    const int c4  = (t & 15) << 2;
    const int sub = t >> 4;           // 0..15

    const int h0 = ph * 64 + rc * 4;
    const int w0 = pw * 64;
    const float* xb = x + (((size_t)b * HH + h0) * WW + w0) * CC;

    float4 s = make_float4(0.f, 0.f, 0.f, 0.f);
#pragma unroll
    for (int k = 0; k < 16; ++k) {
        const int pos = sub + (k << 4);       // 0..255
        const int row = pos >> 6;
        const int col = pos & 63;
        const float4 v = *(const float4*)(xb + ((size_t)row * WW + col) * CC + c4);
        s.x += v.x; s.y += v.y; s.z += v.z; s.w += v.w;
    }

    __shared__ float lds[16 * 64];
    lds[sub * 64 + c4 + 0] = s.x;
    lds[sub * 64 + c4 + 1] = s.y;
    lds[sub * 64 + c4 + 2] = s.z;
    lds[sub * 64 + c4 + 3] = s.w;
    __syncthreads();

    if (t < 64) {
        float acc = 0.f;
#pragma unroll
        for (int ss = 0; ss < 16; ++ss) acc += lds[ss * 64 + t];
        part[(((size_t)b * NTOK + n) * 16 + rc) * CC + t] = acc;
    }
}

__global__ __launch_bounds__(256) void pool_partial(const float* __restrict__ x,
                                                    float* __restrict__ part,
                                                    int b0) {
    pool_body(x, part, b0 * 256 + (int)blockIdx.x);
}

// ---------------------------------------------------------------------------
// Stage 2: tokens -> qk -> dots -> softmax -> bf16 MFMA fragments (RNE).
// grid = HALF_B, batch-offset. Phase-1 float4 loads (r8).
// ---------------------------------------------------------------------------
__global__ __launch_bounds__(256) void attn_kernel(const float* __restrict__ part,
                                                   const float* __restrict__ w_qkv, // [32][16]
                                                   unsigned short* __restrict__ fragw,
                                                   int b0) {
    const int b = b0 + blockIdx.x;
    const int t = threadIdx.x;

    __shared__ float tok[CC * NDIM];   // [c][n]
    __shared__ float ql [CC * NDIM];   // [c][n]
    __shared__ float kl [CC * NDIM];   // [c][n]
    __shared__ float dl [CC * CC];     // [i][j]
    __shared__ float rs [CC];          // 1/rowsum

    const float* pb = part + (size_t)b * NTOK * 16 * CC;

    // tokens[c][n] = mean over patch = (sum of 16 rc-partials)/4096
    {
        const int n  = t >> 4;
        const int cq = t & 15;
        float4 a = make_float4(0.f, 0.f, 0.f, 0.f);
#pragma unroll
        for (int rc = 0; rc < 16; ++rc) {
            const float4 v = *(const float4*)(pb + ((size_t)n * 16 + rc) * CC + cq * 4);
            a.x += v.x; a.y += v.y; a.z += v.z; a.w += v.w;
        }
        tok[(cq * 4 + 0) * NDIM + n] = a.x * (1.0f / 4096.0f);
        tok[(cq * 4 + 1) * NDIM + n] = a.y * (1.0f / 4096.0f);
        tok[(cq * 4 + 2) * NDIM + n] = a.z * (1.0f / 4096.0f);
        tok[(cq * 4 + 3) * NDIM + n] = a.w * (1.0f / 4096.0f);
    }
    __syncthreads();

    // qk[c][d] = sum_n tok[c][n] * w[d][n];  split into q (d<16) and k
    for (int idx = t; idx < CC * 32; idx += 256) {
        const int c = idx >> 5, d = idx & 31;
        float a = 0.f;
#pragma unroll
        for (int n = 0; n < NDIM; ++n) a += tok[c * NDIM + n] * w_qkv[d * NDIM + n];
        if (d < 16) ql[c * NDIM + d] = a;
        else        kl[c * NDIM + (d - 16)] = a;
    }
    __syncthreads();

    // dots[i][j] = 0.25 * sum_n q[i][n]*k[j][n]
    for (int idx = t; idx < CC * CC; idx += 256) {
        const int i = idx >> 6, j = idx & 63;
        float a = 0.f;
#pragma unroll
        for (int n = 0; n < NDIM; ++n) a += ql[i * NDIM + n] * kl[j * NDIM + n];
        dl[idx] = a * 0.25f;
    }
    __syncthreads();

    // row softmax (64 rows, one thread each — tiny)
    if (t < CC) {
        float m = -1e30f;
        for (int j = 0; j < CC; ++j) m = fmaxf(m, dl[t * CC + j]);
        float ssum = 0.f;
        for (int j = 0; j < CC; ++j) {
            const float e = expf(dl[t * CC + j] - m);
            dl[t * CC + j] = e;
            ssum += e;
        }
        rs[t] = 1.0f / ssum;
    }
    __syncthreads();

    // Emit attn[t][c] = dl[t][c]*rs[t] as bf16 MFMA fragments.
    for (int idx = t; idx < 512; idx += 256) {
        const int tt   = idx >> 3;          // 0..63
        const int oct  = idx & 7;           // c octet
        const int ks   = oct >> 2;          // kstep = c>>5
        const int g    = oct & 3;           // lane>>4 group
        const int slot = (tt >> 4) * 2 + ks;         // 0..7
        const int lanei = (tt & 15) + g * 16;
        const float rr = rs[tt];
        s16x8 hi;
#pragma unroll
        for (int j = 0; j < 8; ++j)
            hi[j] = (short)f2bf_rne(dl[tt * CC + oct * 8 + j] * rr);
        s16x8* dst = (s16x8*)fragw + ((size_t)b * 8 + slot) * 64;
        dst[lanei] = hi;
    }
}

// ---------------------------------------------------------------------------
// Out body (v10, verbatim math): operand-swapped single-bf16 MFMA GEMM,
// float4 stores. D = attn x x^T -> row=t, col=pixel.
// ---------------------------------------------------------------------------
__device__ __forceinline__ float gelu_fast(float v) {
    // gelu ~= v * sigmoid(1.59576912v + 0.07135482v^3); |err|<2e-4 for |v|<~1.
    const float u = v * v;
    const float z = v * fmaf(0.07135482f, u, 1.59576912f);
    const float e = exp2f(z * -1.44269504f);            // e^{-z}
    return v * __builtin_amdgcn_rcpf(e + 1.0f);
}

__device__ __forceinline__ s16x8 pack8(const float4 a, const float4 b) {
    union { unsigned int u[4]; s16x8 v; } r;
    asm("v_cvt_pk_bf16_f32 %0, %1, %2" : "=v"(r.u[0]) : "v"(a.x), "v"(a.y));
    asm("v_cvt_pk_bf16_f32 %0, %1, %2" : "=v"(r.u[1]) : "v"(a.z), "v"(a.w));
    asm("v_cvt_pk_bf16_f32 %0, %1, %2" : "=v"(r.u[2]) : "v"(b.x), "v"(b.y));
    asm("v_cvt_pk_bf16_f32 %0, %1, %2" : "=v"(r.u[3]) : "v"(b.z), "v"(b.w));
    return r.v;
}

__device__ __forceinline__ void out_body(const float* __restrict__ x,
                                         const unsigned short* __restrict__ frag,
                                         float* __restrict__ out, int blk) {
    const int tid  = threadIdx.x;
    const int lane = tid & 63;
    const int wv   = tid >> 6;
    const int b    = blk >> 8;            // 256 blocks per batch
    const int row  = lane & 15;           // pixel-in-tile (x rows / D cols)
    const int g    = lane >> 4;

    const size_t pix0 = (size_t)blk * 256 + wv * 64;
    const float* xb = x + (pix0 + row) * CC + g * 8;

    // ---- issue x pixel-tile 0 ----
    float4 a0 = *(const float4*)(xb);
    float4 a1 = *(const float4*)(xb + 4);
    float4 a2 = *(const float4*)(xb + 32);
    float4 a3 = *(const float4*)(xb + 36);

    // ---- issue the 8 per-lane attn fragments (L2-hot, 16 B each) ----
    const s16x8* fb = (const s16x8*)(frag + (size_t)b * FRAG_USHORT_PER_B);
    s16x8 bf[8];
#pragma unroll
    for (int s = 0; s < 8; ++s) bf[s] = fb[s * 64 + lane];

    // ---- issue x pixel-tile 1 ----
    const float* x1 = xb + 16 * CC;
    float4 c0 = *(const float4*)(x1);
    float4 c1 = *(const float4*)(x1 + 4);
    float4 c2 = *(const float4*)(x1 + 32);
    float4 c3 = *(const float4*)(x1 + 36);

    // store base: pixel = lane&15 (D col), t-quad base = g*4 (D rows)
    float* ob = out + (pix0 + row) * CC + (g << 2);

#define TCOLS(PT, XH0, XH1)                                                      \
    _Pragma("unroll")                                                            \
    for (int tt = 0; tt < 4; ++tt) {                                             \
        f32x4 acc = {0.f, 0.f, 0.f, 0.f};                                        \
        acc = __builtin_amdgcn_mfma_f32_16x16x32_bf16(bf[tt * 2], XH0, acc, 0, 0, 0);     \
        acc = __builtin_amdgcn_mfma_f32_16x16x32_bf16(bf[tt * 2 + 1], XH1, acc, 0, 0, 0); \
        f32x4 gv;                                                                \
        gv.x = gelu_fast(acc.x); gv.y = gelu_fast(acc.y);                        \
        gv.z = gelu_fast(acc.z); gv.w = gelu_fast(acc.w);                        \
        *(f32x4*)(ob + (size_t)(PT) * 16 * CC + tt * 16) = gv;                   \
    }

    // pt0: compute from A-buf, prefetch pt2 into A-buf
    {
        const s16x8 xh0 = pack8(a0, a1);
        const s16x8 xh1 = pack8(a2, a3);
        const float* nx = xb + 32 * CC;
        a0 = *(const float4*)(nx);
        a1 = *(const float4*)(nx + 4);
        a2 = *(const float4*)(nx + 32);
        a3 = *(const float4*)(nx + 36);
        TCOLS(0, xh0, xh1)
    }
    // pt1: compute from B-buf, prefetch pt3 into B-buf
    {
        const s16x8 xh0 = pack8(c0, c1);
        const s16x8 xh1 = pack8(c2, c3);
        const float* nx = xb + 48 * CC;
        c0 = *(const float4*)(nx);
        c1 = *(const float4*)(nx + 4);
        c2 = *(const float4*)(nx + 32);
        c3 = *(const float4*)(nx + 36);
        TCOLS(1, xh0, xh1)
    }
    // pt2: compute from A-buf
    {
        const s16x8 xh0 = pack8(a0, a1);
        const s16x8 xh1 = pack8(a2, a3);
        TCOLS(2, xh0, xh1)
    }
    // pt3: compute from B-buf
    {
        const s16x8 xh0 = pack8(c0, c1);
        const s16x8 xh1 = pack8(c2, c3);
        TCOLS(3, xh0, xh1)
    }
#undef TCOLS
}

__global__ __launch_bounds__(256) void out_mfma(const float* __restrict__ x,
                                                const unsigned short* __restrict__ frag,
                                                float* __restrict__ out,
                                                int b0) {
    out_body(x, frag, out, b0 * 256 + (int)blockIdx.x);
}

// ---------------------------------------------------------------------------
// v11: fused out(half A) || pool(half B). Even blocks run out-role, odd run
// pool-role -> every CU hosts a mix from the first dispatch wave (m114:
// co-resident waves overlap to max, not sum). pool's streaming reads fill
// out's HBM-latency bubbles — attacks the measured ~2x-over-traffic-floor
// gap at MACHINE level, the one mechanism r5-r9's within-kernel ablations
// (all null) could not touch. No data dependency: out(A) needs attn(A) only;
// pool(B) is independent; part/frag/out buffers disjoint.
// ---------------------------------------------------------------------------
__global__ __launch_bounds__(256) void fused_out_pool(const float* __restrict__ x,
                                                      const unsigned short* __restrict__ frag,
                                                      float* __restrict__ out,
                                                      float* __restrict__ part,
                                                      int b0_out, int b0_pool) {
    const int blk2 = (int)blockIdx.x;     // 4096
    if (blk2 & 1) pool_body(x, part, b0_pool * 256 + (blk2 >> 1));
    else          out_body(x, frag, out, b0_out * 256 + (blk2 >> 1));
}

// ---------------------------------------------------------------------------
extern "C" void kernel_launch(void* const* d_in, const int* in_sizes, int n_in,
                              void* d_out, int out_size, void* d_ws, size_t ws_size,
                              hipStream_t stream) {
    const float* x     = (const float*)d_in[0];   // (16,256,256,64) fp32
    const float* w_qkv = (const float*)d_in[1];   // (32,16) fp32
    float* out   = (float*)d_out;                 // (16,256,256,64) fp32
    float* part  = (float*)d_ws;                  // 1 MiB
    unsigned short* frag = (unsigned short*)(part + PART_FLOATS); // 128 KiB

    // half0 pool, half0 attn
    pool_partial<<<HALF_B * 256, 256, 0, stream>>>(x, part, 0);
    attn_kernel<<<HALF_B, 256, 0, stream>>>(part, w_qkv, frag, 0);
    // out(half0) overlapped with pool(half1)
    fused_out_pool<<<2 * HALF_B * 256, 256, 0, stream>>>(x, frag, out, part, 0, HALF_B);
    // half1 attn + out
    attn_kernel<<<HALF_B, 256, 0, stream>>>(part, w_qkv, frag, HALF_B);
    out_mfma<<<HALF_B * 256, 256, 0, stream>>>(x, frag, out, HALF_B);
}

// Round 11
// 525.665 us; speedup vs baseline: 1.0362x; 1.0362x over previous
//
#include <hip/hip_runtime.h>
#include <math.h>
#include <cstddef>

// Problem constants
#define BB   16
#define HH   256
#define WW   256
#define CC   64      // channels (= attention token count)
#define NTOK 16      // pooled tokens per (b,c)
#define NDIM 16      // DIM

// ws layout:
//   part : [B][16 tok][16 rc][64 c] fp32  = 262144 floats (1 MiB)
//   frag : [B][8 slot][64 lane][8 j] bf16 =  65536 ushorts (128 KiB)
//   xbf  : [B*H*W][64 c] bf16             = 128 MiB  (bf16 copy of x,
//          written by pool with the SAME v_cvt_pk_bf16_f32 RNE that out's
//          pack8 used -> bit-identical numerics; out never reads fp32 x)
//   SINGLE bf16: attn ~= 1/64 uniform, out in +-0.8; single-RNE-bf16 error
//   max ~1e-3 << 8.7e-3 budget (verified r6-r10, absmax at harness floor).
#define PART_FLOATS (BB * NTOK * 16 * CC)
#define FRAG_USHORT_PER_B (8 * 64 * 8)   // 4096
#define FRAG_TOTAL_USHORT (BB * FRAG_USHORT_PER_B)

typedef short s16x8 __attribute__((ext_vector_type(8)));   // 8 bf16 (4 VGPRs)
typedef float f32x4 __attribute__((ext_vector_type(4)));

__device__ __forceinline__ unsigned short f2bf_rne(float f) {
    unsigned int u = __float_as_uint(f);
    return (unsigned short)((u + 0x7fffu + ((u >> 16) & 1u)) >> 16);
}

// ---------------------------------------------------------------------------
// Stage 1 (v12): partial pooling sums + bf16 transcode of x.
// grid = B*256 blocks. Reads x once (coalesced float4); emits xbf (8 B/lane
// per iter, waves write 512 B contiguous runs) alongside the pool partials.
// ---------------------------------------------------------------------------
__global__ __launch_bounds__(256) void pool_partial(const float* __restrict__ x,
                                                    float* __restrict__ part,
                                                    unsigned short* __restrict__ xbf) {
    const int blk = blockIdx.x;       // b*256 + n*16 + rc
    const int rc  = blk & 15;
    const int n   = (blk >> 4) & 15;
    const int b   = blk >> 8;
    const int ph  = n >> 2, pw = n & 3;
    const int t   = threadIdx.x;
    const int c4  = (t & 15) << 2;
    const int sub = t >> 4;           // 0..15

    const int h0 = ph * 64 + rc * 4;
    const int w0 = pw * 64;
    const size_t pixbase = ((size_t)b * HH + h0) * WW + w0;   // pixel index
    const float* xb = x + pixbase * CC;
    unsigned short* xo = xbf + pixbase * CC;

    float4 s = make_float4(0.f, 0.f, 0.f, 0.f);
#pragma unroll
    for (int k = 0; k < 16; ++k) {
        const int pos = sub + (k << 4);       // 0..255
        const int row = pos >> 6;
        const int col = pos & 63;
        const size_t poff = (size_t)row * WW + col;
        const float4 v = *(const float4*)(xb + poff * CC + c4);
        s.x += v.x; s.y += v.y; s.z += v.z; s.w += v.w;
        // bf16 transcode (RNE, same instr as out's former pack8)
        union { unsigned int u[2]; } r;
        asm("v_cvt_pk_bf16_f32 %0, %1, %2" : "=v"(r.u[0]) : "v"(v.x), "v"(v.y));
        asm("v_cvt_pk_bf16_f32 %0, %1, %2" : "=v"(r.u[1]) : "v"(v.z), "v"(v.w));
        *(uint2*)(xo + poff * CC + c4) = make_uint2(r.u[0], r.u[1]);
    }

    __shared__ float lds[16 * 64];
    lds[sub * 64 + c4 + 0] = s.x;
    lds[sub * 64 + c4 + 1] = s.y;
    lds[sub * 64 + c4 + 2] = s.z;
    lds[sub * 64 + c4 + 3] = s.w;
    __syncthreads();

    if (t < 64) {
        float acc = 0.f;
#pragma unroll
        for (int ss = 0; ss < 16; ++ss) acc += lds[ss * 64 + t];
        part[(((size_t)b * NTOK + n) * 16 + rc) * CC + t] = acc;
    }
}

// ---------------------------------------------------------------------------
// Stage 2: tokens -> qk -> dots -> softmax -> bf16 MFMA fragments (RNE).
// grid = 16 (one per batch). Phase-1 float4 loads (r8).
// ---------------------------------------------------------------------------
__global__ __launch_bounds__(256) void attn_kernel(const float* __restrict__ part,
                                                   const float* __restrict__ w_qkv, // [32][16]
                                                   unsigned short* __restrict__ fragw) {
    const int b = blockIdx.x;
    const int t = threadIdx.x;

    __shared__ float tok[CC * NDIM];   // [c][n]
    __shared__ float ql [CC * NDIM];   // [c][n]
    __shared__ float kl [CC * NDIM];   // [c][n]
    __shared__ float dl [CC * CC];     // [i][j]
    __shared__ float rs [CC];          // 1/rowsum

    const float* pb = part + (size_t)b * NTOK * 16 * CC;

    // tokens[c][n] = mean over patch = (sum of 16 rc-partials)/4096
    {
        const int n  = t >> 4;
        const int cq = t & 15;
        float4 a = make_float4(0.f, 0.f, 0.f, 0.f);
#pragma unroll
        for (int rc = 0; rc < 16; ++rc) {
            const float4 v = *(const float4*)(pb + ((size_t)n * 16 + rc) * CC + cq * 4);
            a.x += v.x; a.y += v.y; a.z += v.z; a.w += v.w;
        }
        tok[(cq * 4 + 0) * NDIM + n] = a.x * (1.0f / 4096.0f);
        tok[(cq * 4 + 1) * NDIM + n] = a.y * (1.0f / 4096.0f);
        tok[(cq * 4 + 2) * NDIM + n] = a.z * (1.0f / 4096.0f);
        tok[(cq * 4 + 3) * NDIM + n] = a.w * (1.0f / 4096.0f);
    }
    __syncthreads();

    // qk[c][d] = sum_n tok[c][n] * w[d][n];  split into q (d<16) and k
    for (int idx = t; idx < CC * 32; idx += 256) {
        const int c = idx >> 5, d = idx & 31;
        float a = 0.f;
#pragma unroll
        for (int n = 0; n < NDIM; ++n) a += tok[c * NDIM + n] * w_qkv[d * NDIM + n];
        if (d < 16) ql[c * NDIM + d] = a;
        else        kl[c * NDIM + (d - 16)] = a;
    }
    __syncthreads();

    // dots[i][j] = 0.25 * sum_n q[i][n]*k[j][n]
    for (int idx = t; idx < CC * CC; idx += 256) {
        const int i = idx >> 6, j = idx & 63;
        float a = 0.f;
#pragma unroll
        for (int n = 0; n < NDIM; ++n) a += ql[i * NDIM + n] * kl[j * NDIM + n];
        dl[idx] = a * 0.25f;
    }
    __syncthreads();

    // row softmax (64 rows, one thread each — tiny)
    if (t < CC) {
        float m = -1e30f;
        for (int j = 0; j < CC; ++j) m = fmaxf(m, dl[t * CC + j]);
        float ssum = 0.f;
        for (int j = 0; j < CC; ++j) {
            const float e = expf(dl[t * CC + j] - m);
            dl[t * CC + j] = e;
            ssum += e;
        }
        rs[t] = 1.0f / ssum;
    }
    __syncthreads();

    // Emit attn[t][c] = dl[t][c]*rs[t] as bf16 MFMA fragments.
    for (int idx = t; idx < 512; idx += 256) {
        const int tt   = idx >> 3;          // 0..63
        const int oct  = idx & 7;           // c octet
        const int ks   = oct >> 2;          // kstep = c>>5
        const int g    = oct & 3;           // lane>>4 group
        const int slot = (tt >> 4) * 2 + ks;         // 0..7
        const int lanei = (tt & 15) + g * 16;
        const float rr = rs[tt];
        s16x8 hi;
#pragma unroll
        for (int j = 0; j < 8; ++j)
            hi[j] = (short)f2bf_rne(dl[tt * CC + oct * 8 + j] * rr);
        s16x8* dst = (s16x8*)fragw + ((size_t)b * 8 + slot) * 64;
        dst[lanei] = hi;
    }
}

// ---------------------------------------------------------------------------
// Stage 3 (v12): operand-swapped single-bf16 MFMA GEMM reading the bf16 x
// copy directly — no fp32 x read, no pack8. float4 stores (v10).
// out[p][t] = gelu(sum_c x[p][c]*attn[t][c]);  D = attn x x^T (row=t, col=p).
// xbf fragment load: lane l -> pixel row=l&15, c = ks*32 + (l>>4)*8 + j
// -> 16 B/lane at xbf[(pix+row)*64 + ks*32 + g*8]. Read traffic halves
// (128 MiB bf16, freshly written by pool -> L3-resident).
// ---------------------------------------------------------------------------
__device__ __forceinline__ float gelu_fast(float v) {
    // gelu ~= v * sigmoid(1.59576912v + 0.07135482v^3); |err|<2e-4 for |v|<~1.
    const float u = v * v;
    const float z = v * fmaf(0.07135482f, u, 1.59576912f);
    const float e = exp2f(z * -1.44269504f);            // e^{-z}
    return v * __builtin_amdgcn_rcpf(e + 1.0f);
}

__global__ __launch_bounds__(256) void out_mfma(const unsigned short* __restrict__ xbf,
                                                const unsigned short* __restrict__ frag,
                                                float* __restrict__ out) {
    const int tid  = threadIdx.x;
    const int lane = tid & 63;
    const int wv   = tid >> 6;
    const int blk  = blockIdx.x;          // 4096 blocks, 256 pixels each
    const int b    = blk >> 8;            // 256 blocks per batch
    const int row  = lane & 15;           // pixel-in-tile (D cols)
    const int g    = lane >> 4;

    const size_t pix0 = (size_t)blk * 256 + wv * 64;
    const unsigned short* xbb = xbf + (pix0 + row) * CC + g * 8;

    // ---- issue x pixel-tile 0 (bf16 fragments, direct) ----
    s16x8 a0 = *(const s16x8*)(xbb);          // ks0
    s16x8 a1 = *(const s16x8*)(xbb + 32);     // ks1

    // ---- issue the 8 per-lane attn fragments (L2-hot, 16 B each) ----
    const s16x8* fb = (const s16x8*)(frag + (size_t)b * FRAG_USHORT_PER_B);
    s16x8 bf[8];
#pragma unroll
    for (int s = 0; s < 8; ++s) bf[s] = fb[s * 64 + lane];

    // ---- issue x pixel-tile 1 ----
    s16x8 c0 = *(const s16x8*)(xbb + 16 * CC);
    s16x8 c1 = *(const s16x8*)(xbb + 16 * CC + 32);

    // store base: pixel = lane&15 (D col), t-quad base = g*4 (D rows)
    float* ob = out + (pix0 + row) * CC + (g << 2);

#define TCOLS(PT, XH0, XH1)                                                      \
    _Pragma("unroll")                                                            \
    for (int tt = 0; tt < 4; ++tt) {                                             \
        f32x4 acc = {0.f, 0.f, 0.f, 0.f};                                        \
        acc = __builtin_amdgcn_mfma_f32_16x16x32_bf16(bf[tt * 2], XH0, acc, 0, 0, 0);     \
        acc = __builtin_amdgcn_mfma_f32_16x16x32_bf16(bf[tt * 2 + 1], XH1, acc, 0, 0, 0); \
        f32x4 gv;                                                                \
        gv.x = gelu_fast(acc.x); gv.y = gelu_fast(acc.y);                        \
        gv.z = gelu_fast(acc.z); gv.w = gelu_fast(acc.w);                        \
        *(f32x4*)(ob + (size_t)(PT) * 16 * CC + tt * 16) = gv;                   \
    }

    // pt0: compute from A-buf, prefetch pt2 into A-buf
    {
        const s16x8 xh0 = a0, xh1 = a1;
        a0 = *(const s16x8*)(xbb + 32 * CC);
        a1 = *(const s16x8*)(xbb + 32 * CC + 32);
        TCOLS(0, xh0, xh1)
    }
    // pt1: compute from B-buf, prefetch pt3 into B-buf
    {
        const s16x8 xh0 = c0, xh1 = c1;
        c0 = *(const s16x8*)(xbb + 48 * CC);
        c1 = *(const s16x8*)(xbb + 48 * CC + 32);
        TCOLS(1, xh0, xh1)
    }
    // pt2: compute from A-buf
    TCOLS(2, a0, a1)
    // pt3: compute from B-buf
    TCOLS(3, c0, c1)
#undef TCOLS
}

// ---------------------------------------------------------------------------
extern "C" void kernel_launch(void* const* d_in, const int* in_sizes, int n_in,
                              void* d_out, int out_size, void* d_ws, size_t ws_size,
                              hipStream_t stream) {
    const float* x     = (const float*)d_in[0];   // (16,256,256,64) fp32
    const float* w_qkv = (const float*)d_in[1];   // (32,16) fp32
    float* out   = (float*)d_out;                 // (16,256,256,64) fp32
    float* part  = (float*)d_ws;                  // 1 MiB
    unsigned short* frag = (unsigned short*)(part + PART_FLOATS); // 128 KiB
    unsigned short* xbf  = frag + FRAG_TOTAL_USHORT;              // 128 MiB

    pool_partial<<<BB * NTOK * 16, 256, 0, stream>>>(x, part, xbf);
    attn_kernel<<<BB, 256, 0, stream>>>(part, w_qkv, frag);
    out_mfma<<<BB * 256, 256, 0, stream>>>(xbf, frag, out);
}

// Round 12
// 514.150 us; speedup vs baseline: 1.0594x; 1.0224x over previous
//
#include <hip/hip_runtime.h>
#include <math.h>
#include <cstddef>

// Problem constants
#define BB   16
#define HH   256
#define WW   256
#define CC   64      // channels (= attention token count)
#define NTOK 16      // pooled tokens per (b,c)
#define NDIM 16      // DIM

// ws layout:
//   part : [B][16 tok][16 rc][64 c] fp32  = 262144 floats (1 MiB)
//   frag : [B][8 slot][64 lane][8 j] bf16 =  65536 ushorts (128 KiB)
//     per-batch: 8*64*8 = 4096 ushorts = 512 fragments of 16 B.
//     slot = tt*2 + kstep
//     element: W[t = tt*16 + (lane&15)][c = kstep*32 + (lane>>4)*8 + j]
//     Same lane mapping serves as A-frag (row=t) or B-frag (col=t) of
//     mfma_f32_16x16x32_bf16 — used as the A operand (v10).
//   SINGLE bf16: attn ~= 1/64 uniform (dots ~ +-2.4e-4), out in +-0.8;
//   single-RNE-bf16 error max ~1e-3 << 8.7e-3 budget (verified r6-r11,
//   absmax at the 1.95e-3 harness ref-quantization floor every round).
//
// FINAL CONFIGURATION (v13 = v10 verbatim, reverting r10/r11 regressions).
// Ablation ledger on out_mfma (dur ~112 us, total 507-517 across ALL):
//   r5 traversal order: null        r6 -70% issue count: null
//   r7 LDS/barrier/depth: null      r8 L3 residency steering: null
//   r9 store vectorization: null    r10 stream overlap: -30 (reverted)
//   r11 bf16 input traffic: -10 (reverted)
// Conclusion: out is pinned by HBM read-miss latency (L3 = |x| exactly,
// ~50% miss) interleaved with its mandatory 268 MB store stream; the
// 2x1GiB harness poison fills (~330 us) dominate the timed region.
#define PART_FLOATS (BB * NTOK * 16 * CC)
#define FRAG_USHORT_PER_B (8 * 64 * 8)   // 4096

typedef short s16x8 __attribute__((ext_vector_type(8)));   // 8 bf16 (4 VGPRs)
typedef float f32x4 __attribute__((ext_vector_type(4)));

__device__ __forceinline__ unsigned short f2bf_rne(float f) {
    unsigned int u = __float_as_uint(f);
    return (unsigned short)((u + 0x7fffu + ((u >> 16) & 1u)) >> 16);
}

// ---------------------------------------------------------------------------
// Stage 1: partial pooling sums. Near coalesced-read floor (~48 us).
// ---------------------------------------------------------------------------
__global__ __launch_bounds__(256) void pool_partial(const float* __restrict__ x,
                                                    float* __restrict__ part) {
    const int blk = blockIdx.x;       // b*256 + n*16 + rc
    const int rc  = blk & 15;
    const int n   = (blk >> 4) & 15;
    const int b   = blk >> 8;
    const int ph  = n >> 2, pw = n & 3;
    const int t   = threadIdx.x;
    const int c4  = (t & 15) << 2;
    const int sub = t >> 4;           // 0..15

    const int h0 = ph * 64 + rc * 4;
    const int w0 = pw * 64;
    const float* xb = x + (((size_t)b * HH + h0) * WW + w0) * CC;

    float4 s = make_float4(0.f, 0.f, 0.f, 0.f);
#pragma unroll
    for (int k = 0; k < 16; ++k) {
        const int pos = sub + (k << 4);       // 0..255
        const int row = pos >> 6;
        const int col = pos & 63;
        const float4 v = *(const float4*)(xb + ((size_t)row * WW + col) * CC + c4);
        s.x += v.x; s.y += v.y; s.z += v.z; s.w += v.w;
    }

    __shared__ float lds[16 * 64];
    lds[sub * 64 + c4 + 0] = s.x;
    lds[sub * 64 + c4 + 1] = s.y;
    lds[sub * 64 + c4 + 2] = s.z;
    lds[sub * 64 + c4 + 3] = s.w;
    __syncthreads();

    if (t < 64) {
        float acc = 0.f;
#pragma unroll
        for (int ss = 0; ss < 16; ++ss) acc += lds[ss * 64 + t];
        part[(((size_t)b * NTOK + n) * 16 + rc) * CC + t] = acc;
    }
}

// ---------------------------------------------------------------------------
// Stage 2: tokens -> qk -> dots -> softmax -> bf16 MFMA fragments (RNE).
// grid = 16 (one per batch). Phase-1 float4 loads (r8).
// ---------------------------------------------------------------------------
__global__ __launch_bounds__(256) void attn_kernel(const float* __restrict__ part,
                                                   const float* __restrict__ w_qkv, // [32][16]
                                                   unsigned short* __restrict__ fragw) {
    const int b = blockIdx.x;
    const int t = threadIdx.x;

    __shared__ float tok[CC * NDIM];   // [c][n]
    __shared__ float ql [CC * NDIM];   // [c][n]
    __shared__ float kl [CC * NDIM];   // [c][n]
    __shared__ float dl [CC * CC];     // [i][j]
    __shared__ float rs [CC];          // 1/rowsum

    const float* pb = part + (size_t)b * NTOK * 16 * CC;

    // tokens[c][n] = mean over patch = (sum of 16 rc-partials)/4096
    {
        const int n  = t >> 4;
        const int cq = t & 15;
        float4 a = make_float4(0.f, 0.f, 0.f, 0.f);
#pragma unroll
        for (int rc = 0; rc < 16; ++rc) {
            const float4 v = *(const float4*)(pb + ((size_t)n * 16 + rc) * CC + cq * 4);
            a.x += v.x; a.y += v.y; a.z += v.z; a.w += v.w;
        }
        tok[(cq * 4 + 0) * NDIM + n] = a.x * (1.0f / 4096.0f);
        tok[(cq * 4 + 1) * NDIM + n] = a.y * (1.0f / 4096.0f);
        tok[(cq * 4 + 2) * NDIM + n] = a.z * (1.0f / 4096.0f);
        tok[(cq * 4 + 3) * NDIM + n] = a.w * (1.0f / 4096.0f);
    }
    __syncthreads();

    // qk[c][d] = sum_n tok[c][n] * w[d][n];  split into q (d<16) and k
    for (int idx = t; idx < CC * 32; idx += 256) {
        const int c = idx >> 5, d = idx & 31;
        float a = 0.f;
#pragma unroll
        for (int n = 0; n < NDIM; ++n) a += tok[c * NDIM + n] * w_qkv[d * NDIM + n];
        if (d < 16) ql[c * NDIM + d] = a;
        else        kl[c * NDIM + (d - 16)] = a;
    }
    __syncthreads();

    // dots[i][j] = 0.25 * sum_n q[i][n]*k[j][n]
    for (int idx = t; idx < CC * CC; idx += 256) {
        const int i = idx >> 6, j = idx & 63;
        float a = 0.f;
#pragma unroll
        for (int n = 0; n < NDIM; ++n) a += ql[i * NDIM + n] * kl[j * NDIM + n];
        dl[idx] = a * 0.25f;
    }
    __syncthreads();

    // row softmax (64 rows, one thread each — tiny)
    if (t < CC) {
        float m = -1e30f;
        for (int j = 0; j < CC; ++j) m = fmaxf(m, dl[t * CC + j]);
        float ssum = 0.f;
        for (int j = 0; j < CC; ++j) {
            const float e = expf(dl[t * CC + j] - m);
            dl[t * CC + j] = e;
            ssum += e;
        }
        rs[t] = 1.0f / ssum;
    }
    __syncthreads();

    // Emit attn[t][c] = dl[t][c]*rs[t] as bf16 MFMA fragments.
    for (int idx = t; idx < 512; idx += 256) {
        const int tt   = idx >> 3;          // 0..63
        const int oct  = idx & 7;           // c octet
        const int ks   = oct >> 2;          // kstep = c>>5
        const int g    = oct & 3;           // lane>>4 group
        const int slot = (tt >> 4) * 2 + ks;         // 0..7
        const int lanei = (tt & 15) + g * 16;
        const float rr = rs[tt];
        s16x8 hi;
#pragma unroll
        for (int j = 0; j < 8; ++j)
            hi[j] = (short)f2bf_rne(dl[tt * CC + oct * 8 + j] * rr);
        s16x8* dst = (s16x8*)fragw + ((size_t)b * 8 + slot) * 64;
        dst[lanei] = hi;
    }
}

// ---------------------------------------------------------------------------
// Stage 3 (v10 final): operand-swapped single-bf16 MFMA GEMM, float4 stores.
// out[p][t] = gelu(sum_c x[p][c]*attn[t][c]);  D = attn x x^T (row=t, col=p).
// A-frag/B-frag lane mapping: row/col = l&15, k = (l>>4)*8+j (m89/m92-
// verified, passing r4-r11). Each thread's 4 acc = 4 consecutive t of one
// pixel -> dwordx4 stores.
// ---------------------------------------------------------------------------
__device__ __forceinline__ float gelu_fast(float v) {
    // gelu ~= v * sigmoid(1.59576912v + 0.07135482v^3); |err|<2e-4 for |v|<~1.
    const float u = v * v;
    const float z = v * fmaf(0.07135482f, u, 1.59576912f);
    const float e = exp2f(z * -1.44269504f);            // e^{-z}
    return v * __builtin_amdgcn_rcpf(e + 1.0f);
}

__device__ __forceinline__ s16x8 pack8(const float4 a, const float4 b) {
    union { unsigned int u[4]; s16x8 v; } r;
    asm("v_cvt_pk_bf16_f32 %0, %1, %2" : "=v"(r.u[0]) : "v"(a.x), "v"(a.y));
    asm("v_cvt_pk_bf16_f32 %0, %1, %2" : "=v"(r.u[1]) : "v"(a.z), "v"(a.w));
    asm("v_cvt_pk_bf16_f32 %0, %1, %2" : "=v"(r.u[2]) : "v"(b.x), "v"(b.y));
    asm("v_cvt_pk_bf16_f32 %0, %1, %2" : "=v"(r.u[3]) : "v"(b.z), "v"(b.w));
    return r.v;
}

__global__ __launch_bounds__(256) void out_mfma(const float* __restrict__ x,
                                                const unsigned short* __restrict__ frag,
                                                float* __restrict__ out) {
    const int tid  = threadIdx.x;
    const int lane = tid & 63;
    const int wv   = tid >> 6;
    const int blk  = blockIdx.x;          // 4096 blocks, 256 pixels each
    const int b    = blk >> 8;            // 256 blocks per batch
    const int row  = lane & 15;           // pixel-in-tile (x rows / D cols)
    const int g    = lane >> 4;

    const size_t pix0 = (size_t)blk * 256 + wv * 64;
    const float* xb = x + (pix0 + row) * CC + g * 8;

    // ---- issue x pixel-tile 0 ----
    float4 a0 = *(const float4*)(xb);
    float4 a1 = *(const float4*)(xb + 4);
    float4 a2 = *(const float4*)(xb + 32);
    float4 a3 = *(const float4*)(xb + 36);

    // ---- issue the 8 per-lane attn fragments (L2-hot, 16 B each) ----
    const s16x8* fb = (const s16x8*)(frag + (size_t)b * FRAG_USHORT_PER_B);
    s16x8 bf[8];
#pragma unroll
    for (int s = 0; s < 8; ++s) bf[s] = fb[s * 64 + lane];

    // ---- issue x pixel-tile 1 ----
    const float* x1 = xb + 16 * CC;
    float4 c0 = *(const float4*)(x1);
    float4 c1 = *(const float4*)(x1 + 4);
    float4 c2 = *(const float4*)(x1 + 32);
    float4 c3 = *(const float4*)(x1 + 36);

    // store base: pixel = lane&15 (D col), t-quad base = g*4 (D rows)
    float* ob = out + (pix0 + row) * CC + (g << 2);

#define TCOLS(PT, XH0, XH1)                                                      \
    _Pragma("unroll")                                                            \
    for (int tt = 0; tt < 4; ++tt) {                                             \
        f32x4 acc = {0.f, 0.f, 0.f, 0.f};                                        \
        acc = __builtin_amdgcn_mfma_f32_16x16x32_bf16(bf[tt * 2], XH0, acc, 0, 0, 0);     \
        acc = __builtin_amdgcn_mfma_f32_16x16x32_bf16(bf[tt * 2 + 1], XH1, acc, 0, 0, 0); \
        f32x4 gv;                                                                \
        gv.x = gelu_fast(acc.x); gv.y = gelu_fast(acc.y);                        \
        gv.z = gelu_fast(acc.z); gv.w = gelu_fast(acc.w);                        \
        *(f32x4*)(ob + (size_t)(PT) * 16 * CC + tt * 16) = gv;                   \
    }

    // pt0: compute from A-buf, prefetch pt2 into A-buf
    {
        const s16x8 xh0 = pack8(a0, a1);
        const s16x8 xh1 = pack8(a2, a3);
        const float* nx = xb + 32 * CC;
        a0 = *(const float4*)(nx);
        a1 = *(const float4*)(nx + 4);
        a2 = *(const float4*)(nx + 32);
        a3 = *(const float4*)(nx + 36);
        TCOLS(0, xh0, xh1)
    }
    // pt1: compute from B-buf, prefetch pt3 into B-buf
    {
        const s16x8 xh0 = pack8(c0, c1);
        const s16x8 xh1 = pack8(c2, c3);
        const float* nx = xb + 48 * CC;
        c0 = *(const float4*)(nx);
        c1 = *(const float4*)(nx + 4);
        c2 = *(const float4*)(nx + 32);
        c3 = *(const float4*)(nx + 36);
        TCOLS(1, xh0, xh1)
    }
    // pt2: compute from A-buf
    {
        const s16x8 xh0 = pack8(a0, a1);
        const s16x8 xh1 = pack8(a2, a3);
        TCOLS(2, xh0, xh1)
    }
    // pt3: compute from B-buf
    {
        const s16x8 xh0 = pack8(c0, c1);
        const s16x8 xh1 = pack8(c2, c3);
        TCOLS(3, xh0, xh1)
    }
#undef TCOLS
}

// ---------------------------------------------------------------------------
extern "C" void kernel_launch(void* const* d_in, const int* in_sizes, int n_in,
                              void* d_out, int out_size, void* d_ws, size_t ws_size,
                              hipStream_t stream) {
    const float* x     = (const float*)d_in[0];   // (16,256,256,64) fp32
    const float* w_qkv = (const float*)d_in[1];   // (32,16) fp32
    float* out   = (float*)d_out;                 // (16,256,256,64) fp32
    float* part  = (float*)d_ws;                  // 1 MiB
    unsigned short* frag = (unsigned short*)(part + PART_FLOATS); // 128 KiB

    pool_partial<<<BB * NTOK * 16, 256, 0, stream>>>(x, part);
    attn_kernel<<<BB, 256, 0, stream>>>(part, w_qkv, frag);
    out_mfma<<<BB * 256, 256, 0, stream>>>(x, frag, out);
}